// Round 1
// baseline (296.243 us; speedup 1.0000x reference)
//
#include <hip/hip_runtime.h>
#include <stdint.h>

// Problem: B=4, N=8192, F=64, L=2
//   z = x; repeat 2x: z = relu( A @ z @ W_l )   per batch
// Restructure: relu((A z) W) == relu(A (z W))  -> per layer:
//   1) zw kernel:  Zt[c=b*64+g][n] = sum_f z[b,n,f] * W_l[f,g]   (bf16, K-major = transposed)
//   2) gemm kernel: z_next[m, c]   = relu( sum_k A[m,k] * Zt[c][k] )  (bf16 MFMA, fp32 accum)
// A converted once f32->bf16 into d_ws (128 MiB; fits L3 -> layer-2 A reads are cache hits).
//
// ws layout: [0, 128Mi) A_bf16 | [128Mi, +4Mi) Zt | [+4Mi, +4Mi) z1   => needs 136 MiB ws.

#define MK 8192

typedef float f32x4 __attribute__((ext_vector_type(4)));
typedef uint32_t u32x4 __attribute__((ext_vector_type(4)));
typedef __bf16 bf16x8 __attribute__((ext_vector_type(8)));

__device__ inline uint16_t f2bf(float f) {
  uint32_t u = __builtin_bit_cast(uint32_t, f);
  u += 0x7fffu + ((u >> 16) & 1u);   // round-to-nearest-even (inputs are finite randn)
  return (uint16_t)(u >> 16);
}

// ---------------- A f32 -> bf16 (256 MB read, 128 MB write, pure streaming) ---------------
__global__ __launch_bounds__(256) void cvtA(const float* __restrict__ A, uint16_t* __restrict__ Ab) {
  const uint64_t total = (uint64_t)MK * MK;
  uint64_t i = ((uint64_t)blockIdx.x * 256 + threadIdx.x) * 8;
  const uint64_t stride = (uint64_t)gridDim.x * 256 * 8;
  for (; i < total; i += stride) {
    f32x4 v0 = *(const f32x4*)(A + i);
    f32x4 v1 = *(const f32x4*)(A + i + 4);
    u32x4 w;
    w[0] = (uint32_t)f2bf(v0[0]) | ((uint32_t)f2bf(v0[1]) << 16);
    w[1] = (uint32_t)f2bf(v0[2]) | ((uint32_t)f2bf(v0[3]) << 16);
    w[2] = (uint32_t)f2bf(v1[0]) | ((uint32_t)f2bf(v1[1]) << 16);
    w[3] = (uint32_t)f2bf(v1[2]) | ((uint32_t)f2bf(v1[3]) << 16);
    *(u32x4*)(Ab + i) = w;
  }
}

// ---------------- Zt = (z @ W_l)^T, stored [256][8192] bf16 -------------------------------
// LAYER 0: z = x (f32, [4][8192][64]).  LAYER 1: z = z1 (bf16, [8192][256], c = b*64+f).
template <int LAYER>
__global__ __launch_bounds__(256) void zw_kernel(const float* __restrict__ x,
                                                 const uint16_t* __restrict__ z1,
                                                 const float* __restrict__ net,
                                                 uint16_t* __restrict__ Zt) {
  __shared__ float Wl[64 * 64];     // [f][g], broadcast reads -> no conflicts
  __shared__ float rows[64][65];    // +1 pad: lane-varying row index -> 2-way max
  const int b = blockIdx.y;
  const int n0 = blockIdx.x * 64;
  const int tid = threadIdx.x;

  const float* Wsrc = net + LAYER * 4096;
  for (int i = tid * 4; i < 4096; i += 1024) {
    f32x4 v = *(const f32x4*)(Wsrc + i);
    Wl[i] = v[0]; Wl[i + 1] = v[1]; Wl[i + 2] = v[2]; Wl[i + 3] = v[3];
  }
  if (LAYER == 0) {
    const float* src = x + ((uint64_t)b * MK + n0) * 64;
    for (int i = tid * 4; i < 4096; i += 1024) {
      f32x4 v = *(const f32x4*)(src + i);
      int r = i >> 6, f = i & 63;
      rows[r][f] = v[0]; rows[r][f + 1] = v[1]; rows[r][f + 2] = v[2]; rows[r][f + 3] = v[3];
    }
  } else {
    for (int i = tid * 8; i < 4096; i += 2048) {
      int r = i >> 6, f = i & 63;
      u32x4 v = *(const u32x4*)(z1 + (uint64_t)(n0 + r) * 256 + b * 64 + f);
#pragma unroll
      for (int j = 0; j < 4; ++j) {
        rows[r][f + 2 * j]     = __builtin_bit_cast(float, (v[j] & 0xffffu) << 16);
        rows[r][f + 2 * j + 1] = __builtin_bit_cast(float, v[j] & 0xffff0000u);
      }
    }
  }
  __syncthreads();

  const int nl = tid & 63;            // node within block (lane) -> coalesced writes
  const int g0 = (tid >> 6) * 16;     // output-feature group (wave-uniform)
  float s[16];
#pragma unroll
  for (int j = 0; j < 16; ++j) s[j] = 0.f;
  for (int f = 0; f < 64; ++f) {
    float rv = rows[nl][f];
#pragma unroll
    for (int j = 0; j < 16; ++j) s[j] = fmaf(rv, Wl[f * 64 + g0 + j], s[j]);
  }
  uint16_t* dst = Zt + (uint64_t)(b * 64 + g0) * MK + n0 + nl;
#pragma unroll
  for (int j = 0; j < 16; ++j) dst[(uint64_t)j * MK] = f2bf(s[j]);
}

// ---------------- z_next = relu(A @ Zt^T) : M=8192 N=256 K=8192 bf16 MFMA -----------------
// Tile BM=128 x BN=64, BK=64, 8 waves (512 thr), grid 64x4 = 256 blocks (XCD-swizzled).
// Staging: global_load_lds width 16, LINEAR LDS dest + pre-swizzled GLOBAL src;
// reads XOR-swizzle (ushort idx ^= (row&7)<<3) -> 2 lanes/bank (free).
// MFMA frag convention (guide-verified m89/m91): a: row=lane&15,k=(lane>>4)*8+i (A row-major);
// b: col=lane&15 (from Zt row = col, K-contig); D: col=lane&15,row=(lane>>4)*4+reg.
template <int OUT_MODE>  // 0: write bf16 z1[8192][256]; 1: write f32 out[4][8192][64]
__global__ __launch_bounds__(512) void gemm_relu(const uint16_t* __restrict__ Ab,
                                                 const uint16_t* __restrict__ Bt,
                                                 uint16_t* __restrict__ Zout,
                                                 float* __restrict__ Fout) {
  __shared__ uint16_t As[128 * 64];  // 16 KB, 16 x 1KB wave-chunks
  __shared__ uint16_t Bs[64 * 64];   // 8 KB,  8 x 1KB wave-chunks
  const int bid0 = (int)blockIdx.x;
  const int bid = (bid0 & 7) * 32 + (bid0 >> 3);  // bijective XCD swizzle (256 % 8 == 0)
  const int bm = bid >> 2, bn = bid & 3;
  const int tid = threadIdx.x;
  const int wid = tid >> 6, lane = tid & 63;
  const int wr = wid >> 1, wc = wid & 1;          // wave grid 4x2 over (128, 64)
  const int row0 = bm * 128, col0 = bn * 64;

  f32x4 acc[2][2] = {};

  // staging: 24 chunks (16 A + 8 B), 3 per wave. Lane geometry within a chunk:
  //   linear LDS ushort = c*512 + lane*8  -> row = c*8 + (lane>>3)
  //   swizzled source k = 8 * ((lane&7) ^ (lane>>3))   (inverse of read-side XOR)
  const int lsub = lane >> 3;
  const int kst = ((lane & 7) ^ lsub) << 3;
  const uint16_t* gp[3];
  uint16_t* lp[3];
#pragma unroll
  for (int j = 0; j < 3; ++j) {
    const int c = wid * 3 + j;
    if (c < 16) {
      gp[j] = Ab + (uint64_t)(row0 + c * 8 + lsub) * MK + kst;
      lp[j] = As + c * 512;
    } else {
      gp[j] = Bt + (uint64_t)(col0 + (c - 16) * 8 + lsub) * MK + kst;
      lp[j] = Bs + (c - 16) * 512;
    }
  }

  for (int kt = 0; kt < MK; kt += 64) {
#pragma unroll
    for (int j = 0; j < 3; ++j)
      __builtin_amdgcn_global_load_lds(
          (const __attribute__((address_space(1))) uint32_t*)(gp[j] + kt),
          (__attribute__((address_space(3))) uint32_t*)lp[j], 16, 0, 0);
    __syncthreads();  // compiler drains vmcnt before s_barrier (m97 semantics)

#pragma unroll
    for (int kk = 0; kk < 2; ++kk) {
      const int kb = kk * 32 + ((lane >> 4) << 3);
      const int ra0 = wr * 32 + (lane & 15), ra1 = ra0 + 16;
      const int rb0 = wc * 32 + (lane & 15), rb1 = rb0 + 16;
      bf16x8 a0 = *(const bf16x8*)&As[ra0 * 64 + (kb ^ ((ra0 & 7) << 3))];
      bf16x8 a1 = *(const bf16x8*)&As[ra1 * 64 + (kb ^ ((ra1 & 7) << 3))];
      bf16x8 b0 = *(const bf16x8*)&Bs[rb0 * 64 + (kb ^ ((rb0 & 7) << 3))];
      bf16x8 b1 = *(const bf16x8*)&Bs[rb1 * 64 + (kb ^ ((rb1 & 7) << 3))];
      acc[0][0] = __builtin_amdgcn_mfma_f32_16x16x32_bf16(a0, b0, acc[0][0], 0, 0, 0);
      acc[0][1] = __builtin_amdgcn_mfma_f32_16x16x32_bf16(a0, b1, acc[0][1], 0, 0, 0);
      acc[1][0] = __builtin_amdgcn_mfma_f32_16x16x32_bf16(a1, b0, acc[1][0], 0, 0, 0);
      acc[1][1] = __builtin_amdgcn_mfma_f32_16x16x32_bf16(a1, b1, acc[1][1], 0, 0, 0);
    }
    __syncthreads();
  }

  const int lrow = (lane >> 4) * 4;
  const int lcol = lane & 15;
#pragma unroll
  for (int m = 0; m < 2; ++m)
#pragma unroll
    for (int n = 0; n < 2; ++n) {
      const int grb = row0 + wr * 32 + m * 16 + lrow;
      const int gc = col0 + wc * 32 + n * 16 + lcol;
#pragma unroll
      for (int j = 0; j < 4; ++j) {
        const float v = fmaxf(acc[m][n][j], 0.0f);
        const int gr = grb + j;
        if (OUT_MODE == 0) {
          Zout[(uint64_t)gr * 256 + gc] = f2bf(v);
        } else {
          Fout[(((uint64_t)(gc >> 6)) * MK + gr) * 64 + (gc & 63)] = v;
        }
      }
    }
}

extern "C" void kernel_launch(void* const* d_in, const int* in_sizes, int n_in,
                              void* d_out, int out_size, void* d_ws, size_t ws_size,
                              hipStream_t stream) {
  const float* x   = (const float*)d_in[0];
  const float* net = (const float*)d_in[2];
  const float* A   = (const float*)d_in[3];
  float* out = (float*)d_out;

  uint16_t* Ab = (uint16_t*)d_ws;                                        // 128 MiB
  uint16_t* Zt = (uint16_t*)((char*)d_ws + 134217728ull);                // 4 MiB
  uint16_t* z1 = (uint16_t*)((char*)d_ws + 134217728ull + 4194304ull);   // 4 MiB

  cvtA<<<dim3(2048), dim3(256), 0, stream>>>(A, Ab);
  zw_kernel<0><<<dim3(128, 4), dim3(256), 0, stream>>>(x, (const uint16_t*)nullptr, net, Zt);
  gemm_relu<0><<<dim3(256), dim3(512), 0, stream>>>(Ab, Zt, z1, (float*)nullptr);
  zw_kernel<1><<<dim3(128, 4), dim3(256), 0, stream>>>((const float*)nullptr, z1, net, Zt);
  gemm_relu<1><<<dim3(256), dim3(512), 0, stream>>>(Ab, Zt, (uint16_t*)nullptr, out);
}

// Round 2
// 213.701 us; speedup vs baseline: 1.3862x; 1.3862x over previous
//
#include <hip/hip_runtime.h>
#include <stdint.h>

// Problem: B=4, N=8192, F=64, L=2
//   z = x; repeat 2x: z = relu( A @ z @ W_l )   per batch
// Restructure: relu((A z) W) == relu(A (z W))  -> per layer:
//   1) zw kernel:  Zt[c=b*64+g][n] = sum_f z[b,n,f] * W_l[f,g]   (bf16, K-major)
//   2) gemm_splitk: P[s][m][c] = sum_{k in chunk s} A[m,k] * Zt[c][k]  (bf16 MFMA, fp32 acc)
//   3) combine:     z_next[m][c] = relu(sum_s P[s][m][c])
// A converted once f32->bf16 (128 MiB, L3-resident for all 4 logical reads).
//
// ws layout: [0,128Mi) A_bf16 | [128Mi,+4Mi) Zt | [+4Mi) z1 | [136Mi,+32Mi) P  (ws ~= 1 GiB)

#define MK 8192

typedef float f32x4 __attribute__((ext_vector_type(4)));
typedef uint32_t u32x4 __attribute__((ext_vector_type(4)));
typedef uint32_t u32x2 __attribute__((ext_vector_type(2)));
typedef __bf16 bf16x8 __attribute__((ext_vector_type(8)));

__device__ inline uint16_t f2bf(float f) {
  uint32_t u = __builtin_bit_cast(uint32_t, f);
  u += 0x7fffu + ((u >> 16) & 1u);   // round-to-nearest-even (inputs are finite randn)
  return (uint16_t)(u >> 16);
}

// ---------------- A f32 -> bf16 (256 MB read, 128 MB write, pure streaming) ---------------
__global__ __launch_bounds__(256) void cvtA(const float* __restrict__ A, uint16_t* __restrict__ Ab) {
  const uint64_t total = (uint64_t)MK * MK;
  uint64_t i = ((uint64_t)blockIdx.x * 256 + threadIdx.x) * 8;
  const uint64_t stride = (uint64_t)gridDim.x * 256 * 8;
  for (; i < total; i += stride) {
    f32x4 v0 = *(const f32x4*)(A + i);
    f32x4 v1 = *(const f32x4*)(A + i + 4);
    u32x4 w;
    w[0] = (uint32_t)f2bf(v0[0]) | ((uint32_t)f2bf(v0[1]) << 16);
    w[1] = (uint32_t)f2bf(v0[2]) | ((uint32_t)f2bf(v0[3]) << 16);
    w[2] = (uint32_t)f2bf(v1[0]) | ((uint32_t)f2bf(v1[1]) << 16);
    w[3] = (uint32_t)f2bf(v1[2]) | ((uint32_t)f2bf(v1[3]) << 16);
    *(u32x4*)(Ab + i) = w;
  }
}

// ---------------- Zt = (z @ W_l)^T, stored [256][8192] bf16 -------------------------------
template <int LAYER>
__global__ __launch_bounds__(256) void zw_kernel(const float* __restrict__ x,
                                                 const uint16_t* __restrict__ z1,
                                                 const float* __restrict__ net,
                                                 uint16_t* __restrict__ Zt) {
  __shared__ float Wl[64 * 64];
  __shared__ float rows[64][65];
  const int b = blockIdx.y;
  const int n0 = blockIdx.x * 64;
  const int tid = threadIdx.x;

  const float* Wsrc = net + LAYER * 4096;
  for (int i = tid * 4; i < 4096; i += 1024) {
    f32x4 v = *(const f32x4*)(Wsrc + i);
    Wl[i] = v[0]; Wl[i + 1] = v[1]; Wl[i + 2] = v[2]; Wl[i + 3] = v[3];
  }
  if (LAYER == 0) {
    const float* src = x + ((uint64_t)b * MK + n0) * 64;
    for (int i = tid * 4; i < 4096; i += 1024) {
      f32x4 v = *(const f32x4*)(src + i);
      int r = i >> 6, f = i & 63;
      rows[r][f] = v[0]; rows[r][f + 1] = v[1]; rows[r][f + 2] = v[2]; rows[r][f + 3] = v[3];
    }
  } else {
    for (int i = tid * 8; i < 4096; i += 2048) {
      int r = i >> 6, f = i & 63;
      u32x4 v = *(const u32x4*)(z1 + (uint64_t)(n0 + r) * 256 + b * 64 + f);
#pragma unroll
      for (int j = 0; j < 4; ++j) {
        rows[r][f + 2 * j]     = __builtin_bit_cast(float, (v[j] & 0xffffu) << 16);
        rows[r][f + 2 * j + 1] = __builtin_bit_cast(float, v[j] & 0xffff0000u);
      }
    }
  }
  __syncthreads();

  const int nl = tid & 63;
  const int g0 = (tid >> 6) * 16;
  float s[16];
#pragma unroll
  for (int j = 0; j < 16; ++j) s[j] = 0.f;
  for (int f = 0; f < 64; ++f) {
    float rv = rows[nl][f];
#pragma unroll
    for (int j = 0; j < 16; ++j) s[j] = fmaf(rv, Wl[f * 64 + g0 + j], s[j]);
  }
  uint16_t* dst = Zt + (uint64_t)(b * 64 + g0) * MK + n0 + nl;
#pragma unroll
  for (int j = 0; j < 16; ++j) dst[(uint64_t)j * MK] = f2bf(s[j]);
}

// ---------------- split-K GEMM: P[s] += A[128-tile] @ Zt^T[128-tile], K-chunk 2048 --------
// 256 thr (4 waves 2x2), wave tile 64x64 = 4x4 frags of 16x16x32. Double-buffered LDS,
// single barrier per K-step (prefetch issued before compute, drained at the barrier).
// Swizzle: linear LDS dest + pre-swizzled global src; read octet o ^= (row&7) (verified r1).
__global__ __launch_bounds__(256) void gemm_splitk(const uint16_t* __restrict__ Ab,
                                                   const uint16_t* __restrict__ Bt,
                                                   float* __restrict__ P) {
  __shared__ uint16_t As[2][8192];   // [buf][128 rows x 64 k]  16 KB/buf
  __shared__ uint16_t Bs[2][8192];
  const int bid0 = (int)blockIdx.x;
  const int bid = (bid0 & 7) * 64 + (bid0 >> 3);   // bijective XCD swizzle (512 % 8 == 0)
  const int bm = bid >> 3;            // 0..63   (outer: XCD-mates share the A row panel)
  const int bn = (bid >> 2) & 1;      // 0..1
  const int s  = bid & 3;             // 0..3    K-split chunk
  const int row0 = bm * 128, col0 = bn * 128, k0 = s * 2048;
  const int tid = threadIdx.x, wid = tid >> 6, lane = tid & 63;
  const int wr = wid >> 1, wc = wid & 1;

  f32x4 acc[4][4] = {};

  // staging: 32 chunks of 1 KB (8 rows x 64 k), 8 per wave; 16 A + 16 B.
  //   lane l in chunk: row = c*8 + (l>>3), linear LDS = c*512 + l*8 (ushort)
  //   pre-swizzled source k-octet = (l&7) ^ (l>>3)
  const int lsub = lane >> 3;
  const int kst = ((lane & 7) ^ lsub) << 3;
  const uint16_t* gp[8];
  uint16_t* lp[8];
#pragma unroll
  for (int j = 0; j < 8; ++j) {
    const int c = wid * 8 + j;
    if (c < 16) {
      gp[j] = Ab + (uint64_t)(row0 + c * 8 + lsub) * MK + k0 + kst;
      lp[j] = &As[0][c * 512];
    } else {
      gp[j] = Bt + (uint64_t)(col0 + (c - 16) * 8 + lsub) * MK + k0 + kst;
      lp[j] = &Bs[0][(c - 16) * 512];
    }
  }

  // prologue: stage k-tile 0 into buf 0
#pragma unroll
  for (int j = 0; j < 8; ++j)
    __builtin_amdgcn_global_load_lds(
        (const __attribute__((address_space(1))) uint32_t*)gp[j],
        (__attribute__((address_space(3))) uint32_t*)lp[j], 16, 0, 0);
  __syncthreads();

  int cur = 0;
  for (int kt = 0; kt < 2048; kt += 64) {
    if (kt + 64 < 2048) {
      const int nb = cur ^ 1;
#pragma unroll
      for (int j = 0; j < 8; ++j)
        __builtin_amdgcn_global_load_lds(
            (const __attribute__((address_space(1))) uint32_t*)(gp[j] + kt + 64),
            (__attribute__((address_space(3))) uint32_t*)(lp[j] + nb * 8192), 16, 0, 0);
    }
    const uint16_t* Ac = &As[cur][0];
    const uint16_t* Bc = &Bs[cur][0];
#pragma unroll
    for (int kk = 0; kk < 2; ++kk) {
      bf16x8 a[4], b[4];
#pragma unroll
      for (int m = 0; m < 4; ++m) {
        const int r = wr * 64 + m * 16 + (lane & 15);
        const int o = (kk * 4 + (lane >> 4)) ^ (r & 7);
        a[m] = *(const bf16x8*)&Ac[r * 64 + o * 8];
      }
#pragma unroll
      for (int n = 0; n < 4; ++n) {
        const int r = wc * 64 + n * 16 + (lane & 15);
        const int o = (kk * 4 + (lane >> 4)) ^ (r & 7);
        b[n] = *(const bf16x8*)&Bc[r * 64 + o * 8];
      }
#pragma unroll
      for (int m = 0; m < 4; ++m)
#pragma unroll
        for (int n = 0; n < 4; ++n)
          acc[m][n] = __builtin_amdgcn_mfma_f32_16x16x32_bf16(a[m], b[n], acc[m][n], 0, 0, 0);
    }
    __syncthreads();   // drains vmcnt(0): prefetch landed; everyone done reading buf cur
    cur ^= 1;
  }

  float* Pp = P + (uint64_t)s * (MK * 256);
  const int lrow = (lane >> 4) * 4, lcol = lane & 15;
#pragma unroll
  for (int m = 0; m < 4; ++m)
#pragma unroll
    for (int n = 0; n < 4; ++n) {
      const int gr = row0 + wr * 64 + m * 16 + lrow;
      const int gc = col0 + wc * 64 + n * 16 + lcol;
#pragma unroll
      for (int j = 0; j < 4; ++j)
        Pp[(uint64_t)(gr + j) * 256 + gc] = acc[m][n][j];
    }
}

// ---------------- combine: z = relu(P0+P1+P2+P3); write bf16 z1 or final f32 out ----------
template <int OUT_MODE>  // 0: z1 bf16 [8192][256]; 1: out f32 [4][8192][64]
__global__ __launch_bounds__(256) void combine(const float* __restrict__ P,
                                               uint16_t* __restrict__ z1,
                                               float* __restrict__ out) {
  const uint64_t g = (uint64_t)blockIdx.x * 256 + threadIdx.x;  // 524288 threads, 4 f32 each
  const uint64_t e = g * 4;
  f32x4 v  = *(const f32x4*)&P[e];
  f32x4 v1 = *(const f32x4*)&P[2097152ull + e];
  f32x4 v2 = *(const f32x4*)&P[4194304ull + e];
  f32x4 v3 = *(const f32x4*)&P[6291456ull + e];
  v = v + v1 + v2 + v3;
#pragma unroll
  for (int j = 0; j < 4; ++j) v[j] = fmaxf(v[j], 0.0f);
  if (OUT_MODE == 0) {
    u32x2 w;
    w[0] = (uint32_t)f2bf(v[0]) | ((uint32_t)f2bf(v[1]) << 16);
    w[1] = (uint32_t)f2bf(v[2]) | ((uint32_t)f2bf(v[3]) << 16);
    *(u32x2*)&z1[e] = w;
  } else {
    const int m = (int)(e >> 8);
    const int c = (int)(e & 255);
    *(f32x4*)&out[(((uint64_t)(c >> 6)) * MK + m) * 64 + (c & 63)] = v;
  }
}

extern "C" void kernel_launch(void* const* d_in, const int* in_sizes, int n_in,
                              void* d_out, int out_size, void* d_ws, size_t ws_size,
                              hipStream_t stream) {
  const float* x   = (const float*)d_in[0];
  const float* net = (const float*)d_in[2];
  const float* A   = (const float*)d_in[3];
  float* out = (float*)d_out;

  uint16_t* Ab = (uint16_t*)d_ws;                                        // 128 MiB
  uint16_t* Zt = (uint16_t*)((char*)d_ws + 134217728ull);                // 4 MiB
  uint16_t* z1 = (uint16_t*)((char*)d_ws + 138412032ull);                // 4 MiB
  float*    P  = (float*)   ((char*)d_ws + 142606336ull);                // 32 MiB

  cvtA<<<dim3(2048), dim3(256), 0, stream>>>(A, Ab);
  zw_kernel<0><<<dim3(128, 4), dim3(256), 0, stream>>>(x, (const uint16_t*)nullptr, net, Zt);
  gemm_splitk<<<dim3(512), dim3(256), 0, stream>>>(Ab, Zt, P);
  combine<0><<<dim3(2048), dim3(256), 0, stream>>>(P, z1, (float*)nullptr);
  zw_kernel<1><<<dim3(128, 4), dim3(256), 0, stream>>>((const float*)nullptr, z1, net, Zt);
  gemm_splitk<<<dim3(512), dim3(256), 0, stream>>>(Ab, Zt, P);
  combine<1><<<dim3(2048), dim3(256), 0, stream>>>(P, (uint16_t*)nullptr, out);
}